// Round 8
// baseline (122.075 us; speedup 1.0000x reference)
//
#include <hip/hip_runtime.h>
#include <math.h>

#define BIGV  1.0e8f
#define PLANE (512 * 512)            // 262144
#define NTOT  (8 * PLANE)            // 2097152
#define PROWS 640                    // 64 pad + 512 + 64 pad
#define PSTRIDE (PROWS * 512)        // floats per padded plane

// ---------------------------------------------------------------------------
// Kernel 1: 1-D DT along axis 3 (binary input) via ballot-built 512-bit line
// mask + clz/ffs nearest-set-bit. Writes h^2 (f32, exact) into a PADDED plane
// layout: row i2 lives at (64+i2); rows 0..63 and 576..639 are BIG pads.
// Blocks >= 4096 write the pads; pad thread 0 zeroes the finalize counter.
// ---------------------------------------------------------------------------
__global__ __launch_bounds__(512) void dt_axis3(const int* __restrict__ y,
                                                float* __restrict__ g1p,
                                                unsigned int* __restrict__ counter) {
    int blk = blockIdx.x;
    if (blk >= 4096) {                                 // pad writer: 1024 blocks
        int idx = (blk - 4096) * 512 + threadIdx.x;    // [0, 524288)
        int plane = idx >> 16;
        int rem   = idx & 65535;
        int r     = rem >> 9;                          // 0..127
        int c     = rem & 511;
        int row   = (r < 64) ? r : (r + 512);          // 0..63 or 576..639
        g1p[plane * PSTRIDE + row * 512 + c] = BIGV;
        if (idx == 0) *counter = 0u;
        return;
    }
    __shared__ unsigned long long words[8];
    int i = threadIdx.x;                               // position in line
    int e = blk * 512 + i;                             // y index (lines contiguous)
    unsigned long long bal = __ballot(y[e] != 0);
    int wid  = i >> 6;
    int lane = i & 63;
    if (lane == 0) words[wid] = bal;
    __syncthreads();

    int k = wid, b = lane;
    int dr = 1 << 30;
    {
        unsigned long long m0 = words[k] & (~0ull << b);
        if (m0) {
            dr = (__ffsll((long long)m0) - 1) - b;
        } else {
            #pragma unroll
            for (int k2 = 0; k2 < 8; ++k2) {
                if (k2 > k && dr == (1 << 30) && words[k2]) {
                    dr = (k2 << 6) + (__ffsll((long long)words[k2]) - 1) - i;
                }
            }
        }
    }
    int dl = 1 << 30;
    {
        unsigned long long m0 = words[k] & (~0ull >> (63 - b));
        if (m0) {
            dl = b - (63 - __clzll((long long)m0));
        } else {
            #pragma unroll
            for (int k2 = 7; k2 >= 0; --k2) {
                if (k2 < k && dl == (1 << 30) && words[k2]) {
                    dl = i - ((k2 << 6) + 63 - __clzll((long long)words[k2]));
                }
            }
        }
    }
    int d = min(dl, dr);
    float h2 = (d > 511) ? BIGV : (float)(d * d);      // exact: d*d < 2^24
    int bb = blk >> 9, i2 = blk & 511;
    g1p[bb * PSTRIDE + (64 + i2) * 512 + i] = h2;
}

// ---------------------------------------------------------------------------
// Kernel 2 (fused): one thread per spatial pixel (i2,i3). Scans the axis-2
// parabola candidates for ALL 8 batches jointly (16 independent coalesced
// loads/iter; exit at the thread's max over 8 — only ~1.2x the per-pixel
// radius at wave granularity). The 8 results stay in registers for the 8x8
// axis-0 min-plus + sqrt + sigmoid(x)*d, then a deterministic block/global
// reduction (last-arriving block does the fixed-order final sum).
// ---------------------------------------------------------------------------
__device__ inline double wave_reduce_d(double v) {
    #pragma unroll
    for (int off = 32; off > 0; off >>= 1) v += __shfl_down(v, off, 64);
    return v;
}

__global__ __launch_bounds__(256) void dt2_axis0_epilogue(
        const float* __restrict__ g1p,
        const float* __restrict__ x,
        double* __restrict__ partials,
        unsigned int* __restrict__ counter,
        float* __restrict__ out) {
    int s  = blockIdx.x * 256 + threadIdx.x;           // spatial [0, PLANE)
    int i2 = s >> 9;
    int i3 = s & 511;

    const float* up[8];
    const float* dn[8];
    float m[8];
    float mmax = 0.0f;
    #pragma unroll
    for (int b = 0; b < 8; ++b) {
        const float* base = g1p + b * PSTRIDE + (64 + i2) * 512 + i3;
        up[b] = base; dn[b] = base;
        m[b] = *base;
        mmax = fmaxf(mmax, m[b]);
    }

    int r = 1;
    for (; r < 64; ++r) {
        float fr2 = (float)(r * r);
        if (fr2 >= mmax) break;
        float nm = 0.0f;
        #pragma unroll
        for (int b = 0; b < 8; ++b) {
            up[b] -= 512; dn[b] += 512;
            m[b] = fminf(m[b], fminf(*up[b], *dn[b]) + fr2);  // pads BIG
            nm = fmaxf(nm, m[b]);
        }
        mmax = nm;
    }
    if (r == 64) {                                     // ultra-rare exact tail
        #pragma unroll
        for (int b = 0; b < 8; ++b) {
            for (int rr = 64; rr < 512; ++rr) {
                float fr2 = (float)(rr * rr);
                if (fr2 >= m[b]) break;
                int upr = i2 - rr, dnr = i2 + rr;
                if (upr < 0 && dnr >= 512) break;
                if (upr >= 0)
                    m[b] = fminf(m[b], g1p[b * PSTRIDE + (64 + upr) * 512 + i3] + fr2);
                if (dnr < 512)
                    m[b] = fminf(m[b], g1p[b * PSTRIDE + (64 + dnr) * 512 + i3] + fr2);
            }
        }
    }

    // ---- axis-0 (8x8 min-plus) + sigmoid + accumulate -------------------
    double acc = 0.0;
    #pragma unroll
    for (int b = 0; b < 8; ++b) {
        float mm = BIGV;
        #pragma unroll
        for (int bp = 0; bp < 8; ++bp) {
            float db = (float)((b - bp) * (b - bp));   // compile-time const
            mm = fminf(mm, m[bp] + db);
        }
        float xv  = x[b * PLANE + s];
        float sig = 1.0f / (1.0f + expf(-xv));
        acc += (double)(sig * sqrtf(mm));
    }

    // ---- deterministic reduction ----------------------------------------
    __shared__ double lds[4];
    __shared__ int is_last;
    double w = wave_reduce_d(acc);
    int lane = threadIdx.x & 63;
    int wid  = threadIdx.x >> 6;
    if (lane == 0) lds[wid] = w;
    __syncthreads();
    if (threadIdx.x == 0) {
        double tsum = lds[0] + lds[1] + lds[2] + lds[3];
        __hip_atomic_store(&partials[blockIdx.x], tsum, __ATOMIC_RELEASE,
                           __HIP_MEMORY_SCOPE_AGENT);
        unsigned int done = __hip_atomic_fetch_add(counter, 1u, __ATOMIC_ACQ_REL,
                                                   __HIP_MEMORY_SCOPE_AGENT);
        is_last = (done == gridDim.x - 1) ? 1 : 0;
    }
    __syncthreads();
    if (is_last) {
        double a = 0.0;
        for (int i = threadIdx.x; i < 1024; i += 256)
            a += __hip_atomic_load(&partials[i], __ATOMIC_ACQUIRE,
                                   __HIP_MEMORY_SCOPE_AGENT);
        double ww = wave_reduce_d(a);
        if (lane == 0) lds[wid] = ww;
        __syncthreads();
        if (threadIdx.x == 0)
            out[0] = (float)((lds[0] + lds[1] + lds[2] + lds[3]) / (double)NTOT);
    }
}

// ---------------------------------------------------------------------------
extern "C" void kernel_launch(void* const* d_in, const int* in_sizes, int n_in,
                              void* d_out, int out_size, void* d_ws, size_t ws_size,
                              hipStream_t stream) {
    const float* x = (const float*)d_in[0];
    const int*   y = (const int*)d_in[1];
    float* out = (float*)d_out;

    float*  g1p      = (float*)d_ws;                   // 10.5 MB padded
    double* partials = (double*)(g1p + 8 * PSTRIDE);   // 8 KB (1024 doubles)
    unsigned int* counter = (unsigned int*)(partials + 1024);

    dt_axis3<<<5120, 512, 0, stream>>>(y, g1p, counter);
    dt2_axis0_epilogue<<<PLANE / 256, 256, 0, stream>>>(g1p, x, partials, counter, out);
}